// Round 1
// baseline (442.845 us; speedup 1.0000x reference)
//
#include <hip/hip_runtime.h>

typedef __attribute__((ext_vector_type(8))) short short8;
typedef __attribute__((ext_vector_type(4))) float f32x4;

#define NB    32
#define CINC  64
#define COUTC 64
#define HWDIM 128
#define NPIX  16384
#define XT_H  130
#define ADIMC 64
#define WTOT  36864   // COUT*CIN*9

__device__ inline unsigned short f2bf(float f) {
    unsigned int u = __float_as_uint(f);
    u += 0x7FFF + ((u >> 16) & 1);   // RNE
    return (unsigned short)(u >> 16);
}

// ---------------------------------------------------------------------------
// prep: x [32,64,128,128] fp32 NCHW -> xt [32,130,130,64] bf16 padded NHWC
//       + fused global-avg-pool partial sums (atomicAdd into pooled[32*64])
// grid (128 hrows, 32 b), 256 threads
// ---------------------------------------------------------------------------
__global__ __launch_bounds__(256) void prep_kernel(
        const float* __restrict__ x, float* __restrict__ pooled,
        unsigned short* __restrict__ xt) {
    __shared__ float lds[CINC][132];   // [c][w], stride 132 floats (16B-aligned rows)
    const int b = blockIdx.y, hrow = blockIdx.x, t = threadIdx.x;

    // phase 1: coalesced float4 reads along w, transpose into LDS, pool partials
    #pragma unroll
    for (int it = 0; it < 8; ++it) {
        const int c  = (t >> 5) + it * 8;
        const int w4 = (t & 31) * 4;
        f32x4 v = *(const f32x4*)(x + (((size_t)b * CINC + c) * HWDIM + hrow) * HWDIM + w4);
        *(f32x4*)&lds[c][w4] = v;
        float s = v[0] + v[1] + v[2] + v[3];
        for (int off = 16; off > 0; off >>= 1) s += __shfl_down(s, off, 32);
        if ((t & 31) == 0) atomicAdd(&pooled[b * CINC + c], s);
    }
    __syncthreads();

    // phase 2: write NHWC bf16, 16B per lane, fully coalesced
    for (int q = t; q < 1024; q += 256) {
        const int w = q >> 3, cg = (q & 7) * 8;
        short8 o;
        #pragma unroll
        for (int i = 0; i < 8; ++i) o[i] = (short)f2bf(lds[cg + i][w]);
        *(short8*)(xt + (((size_t)b * XT_H + hrow + 1) * XT_H + (w + 1)) * CINC + cg) = o;
    }

    // halo zeroing
    if (hrow == 0) {
        unsigned int* r0 = (unsigned int*)(xt + (size_t)b * XT_H * XT_H * CINC);
        for (int i = t; i < XT_H * CINC / 2; i += 256) r0[i] = 0u;
    }
    if (hrow == HWDIM - 1) {
        unsigned int* r129 = (unsigned int*)(xt + ((size_t)b * XT_H + 129) * XT_H * CINC);
        for (int i = t; i < XT_H * CINC / 2; i += 256) r129[i] = 0u;
    }
    if (t < 64) {
        const int wc = (t < 32) ? 0 : 129;
        unsigned int* p = (unsigned int*)(xt + (((size_t)b * XT_H + hrow + 1) * XT_H + wc) * CINC);
        p[t & 31] = 0u;
    }
}

// ---------------------------------------------------------------------------
// mlp1: h = relu(pooled/16384 @ w1 + b1)   [32,64]
// ---------------------------------------------------------------------------
__global__ __launch_bounds__(256) void mlp1_kernel(
        const float* __restrict__ pooled, const float* __restrict__ w1,
        const float* __restrict__ b1, float* __restrict__ hout) {
    const int tid = blockIdx.x * 256 + threadIdx.x;   // 0..2047
    const int b = tid >> 6, j = tid & 63;
    float acc = b1[j];
    for (int k = 0; k < CINC; ++k)
        acc = fmaf(pooled[b * CINC + k] * (1.0f / NPIX), w1[k * ADIMC + j], acc);
    hout[tid] = fmaxf(acc, 0.0f);
}

// ---------------------------------------------------------------------------
// adapt: a = tanh(h @ w2 + b2); adapted = base_w + scale*a
// emitted bf16 in layout [b][e=ky*3+kx][cout][cin]
// grid 128 blocks x 320 threads; block covers 32 (cout,cin) pairs x 9 e x 32 b
// ---------------------------------------------------------------------------
__global__ __launch_bounds__(320) void adapt_kernel(
        const float* __restrict__ hin, const float* __restrict__ w2,
        const float* __restrict__ b2, const float* __restrict__ base_w,
        const float* __restrict__ scale_p, unsigned short* __restrict__ adp) {
    __shared__ float lh[NB * ADIMC];
    __shared__ unsigned short lo[288 * 33];
    const int t = threadIdx.x, blk = blockIdx.x;
    for (int i = t; i < NB * ADIMC; i += 320) lh[i] = hin[i];
    __syncthreads();
    const float sc = scale_p[0];

    if (t < 288) {
        const int j = blk * 288 + t;
        float acc[NB];
        #pragma unroll
        for (int b = 0; b < NB; ++b) acc[b] = 0.0f;
        for (int k = 0; k < ADIMC; ++k) {
            const float wv = w2[(size_t)k * WTOT + j];
            #pragma unroll
            for (int b = 0; b < NB; ++b) acc[b] = fmaf(lh[b * ADIMC + k], wv, acc[b]);
        }
        const float bw = base_w[j], bb = b2[j];
        #pragma unroll
        for (int b = 0; b < NB; ++b) {
            const float val = bw + sc * tanhf(acc[b] + bb);
            lo[t * 33 + b] = f2bf(val);
        }
    }
    __syncthreads();

    const int co = blk >> 1, ci0 = (blk & 1) * 32;
    for (int o = t; o < 9216; o += 320) {
        const int b = o / 288;
        const int rem = o - b * 288;
        const int e = rem >> 5, ci = rem & 31;
        adp[(((size_t)b * 9 + e) * COUTC + co) * CINC + ci0 + ci] = lo[(ci * 9 + e) * 33 + b];
    }
}

// ---------------------------------------------------------------------------
// conv: 9 shifted GEMMs via mfma_f32_16x16x32_bf16
// block: 256 thr (4 waves), M=64 (all couts), N=256 pixels (2 rows x 128)
// wave: 4 M-frags x 4 N-frags, K-loop = 9 shifts x 2 cin-chunks of 32
// grid (64 tiles, 32 b)  -> same-b blocks adjacent for L2 locality
// ---------------------------------------------------------------------------
__global__ __launch_bounds__(256) void conv_kernel(
        const unsigned short* __restrict__ xt, const unsigned short* __restrict__ adp,
        const float* __restrict__ base_b, float* __restrict__ out) {
    const int b = blockIdx.y, tile = blockIdx.x, t = threadIdx.x;
    const int wv = t >> 6, lane = t & 63, lm = lane & 15, lq = lane >> 4;
    const int h0 = tile * 2 + (wv >> 1);
    const int wc = (wv & 1) * 64;

    f32x4 acc[4][4];
    #pragma unroll
    for (int mi = 0; mi < 4; ++mi)
        #pragma unroll
        for (int ni = 0; ni < 4; ++ni) acc[mi][ni] = (f32x4){0.f, 0.f, 0.f, 0.f};

    // A: adp[b][e][cout][cin]; lane: cout = mi*16+lm, cin = kc*32 + lq*8
    const unsigned short* Abase = adp + (((size_t)b * 9) * COUTC + lm) * CINC + lq * 8;
    // B: xt[b][h0+ky][wc+lm+ni*16+kx][kc*32+lq*8]
    const unsigned short* Bbase = xt + (((size_t)b * XT_H + h0) * XT_H + wc + lm) * CINC + lq * 8;

    #pragma unroll
    for (int ky = 0; ky < 3; ++ky) {
        #pragma unroll
        for (int kx = 0; kx < 3; ++kx) {
            const unsigned short* Ae = Abase + (size_t)(ky * 3 + kx) * COUTC * CINC;
            const unsigned short* Bp = Bbase + (size_t)(ky * XT_H + kx) * CINC;
            #pragma unroll
            for (int kc = 0; kc < 2; ++kc) {
                short8 af[4], bf[4];
                #pragma unroll
                for (int mi = 0; mi < 4; ++mi)
                    af[mi] = *(const short8*)(Ae + mi * 16 * CINC + kc * 32);
                #pragma unroll
                for (int ni = 0; ni < 4; ++ni)
                    bf[ni] = *(const short8*)(Bp + ni * 16 * CINC + kc * 32);
                #pragma unroll
                for (int mi = 0; mi < 4; ++mi)
                    #pragma unroll
                    for (int ni = 0; ni < 4; ++ni)
                        acc[mi][ni] = __builtin_amdgcn_mfma_f32_16x16x32_bf16(
                            af[mi], bf[ni], acc[mi][ni], 0, 0, 0);
            }
        }
    }

    // epilogue: D row = lq*4+r (cout offset), col = lm (pixel offset)
    const int pixbase = h0 * HWDIM + wc + lm;
    #pragma unroll
    for (int mi = 0; mi < 4; ++mi) {
        #pragma unroll
        for (int r = 0; r < 4; ++r) {
            const int cout = mi * 16 + lq * 4 + r;
            const float bb = base_b[cout];
            #pragma unroll
            for (int ni = 0; ni < 4; ++ni)
                out[((size_t)(b * COUTC + cout) << 14) + pixbase + ni * 16] = acc[mi][ni][r] + bb;
        }
    }
}

// ---------------------------------------------------------------------------
extern "C" void kernel_launch(void* const* d_in, const int* in_sizes, int n_in,
                              void* d_out, int out_size, void* d_ws, size_t ws_size,
                              hipStream_t stream) {
    const float* x      = (const float*)d_in[0];
    const float* base_w = (const float*)d_in[1];
    const float* base_b = (const float*)d_in[2];
    const float* w1     = (const float*)d_in[3];
    const float* b1     = (const float*)d_in[4];
    const float* w2     = (const float*)d_in[5];
    const float* b2     = (const float*)d_in[6];
    const float* scale  = (const float*)d_in[7];
    float* out = (float*)d_out;

    // workspace layout
    unsigned short* xt  = (unsigned short*)d_ws;                        // 69,222,400 B
    unsigned short* adp = (unsigned short*)((char*)d_ws + 69222400);    //  2,359,296 B
    float* pooled       = (float*)((char*)d_ws + 71581696);             //      8,192 B
    float* hbuf         = (float*)((char*)d_ws + 71589888);             //      8,192 B

    hipMemsetAsync(pooled, 0, NB * CINC * sizeof(float), stream);
    prep_kernel<<<dim3(HWDIM, NB), 256, 0, stream>>>(x, pooled, xt);
    mlp1_kernel<<<8, 256, 0, stream>>>(pooled, w1, b1, hbuf);
    adapt_kernel<<<128, 320, 0, stream>>>(hbuf, w2, b2, base_w, scale, adp);
    conv_kernel<<<dim3(64, NB), 256, 0, stream>>>(xt, adp, base_b, out);
}

// Round 2
// 426.692 us; speedup vs baseline: 1.0379x; 1.0379x over previous
//
#include <hip/hip_runtime.h>

typedef __attribute__((ext_vector_type(8))) short short8;
typedef __attribute__((ext_vector_type(4))) float f32x4;

#define NB    32
#define CINC  64
#define COUTC 64
#define HWDIM 128
#define NPIX  16384
#define XT_H  130
#define ADIMC 64
#define WTOT  36864   // COUT*CIN*9

__device__ inline unsigned short f2bf(float f) {
    unsigned int u = __float_as_uint(f);
    u += 0x7FFF + ((u >> 16) & 1);   // RNE
    return (unsigned short)(u >> 16);
}

// ---------------------------------------------------------------------------
// prep: x [32,64,128,128] fp32 NCHW -> xt [32,130,130,64] bf16 padded NHWC
//       + per-(b,hrow) pool partials (plain stores, no atomics)
// grid (128 hrows, 32 b), 256 threads
// ---------------------------------------------------------------------------
__global__ __launch_bounds__(256) void prep_kernel(
        const float* __restrict__ x, float* __restrict__ partial,
        unsigned short* __restrict__ xt) {
    __shared__ float lds[CINC][132];
    const int b = blockIdx.y, hrow = blockIdx.x, t = threadIdx.x;

    // phase 1: coalesced float4 reads along w, transpose into LDS, pool partials
    #pragma unroll
    for (int it = 0; it < 8; ++it) {
        const int c  = (t >> 5) + it * 8;
        const int w4 = (t & 31) * 4;
        f32x4 v = *(const f32x4*)(x + (((size_t)b * CINC + c) * HWDIM + hrow) * HWDIM + w4);
        *(f32x4*)&lds[c][w4] = v;
        float s = v[0] + v[1] + v[2] + v[3];
        for (int off = 16; off > 0; off >>= 1) s += __shfl_down(s, off, 32);
        if ((t & 31) == 0) partial[((size_t)b * HWDIM + hrow) * CINC + c] = s;
    }
    __syncthreads();

    // phase 2: write NHWC bf16, 16B per lane, fully coalesced
    for (int q = t; q < 1024; q += 256) {
        const int w = q >> 3, cg = (q & 7) * 8;
        short8 o;
        #pragma unroll
        for (int i = 0; i < 8; ++i) o[i] = (short)f2bf(lds[cg + i][w]);
        *(short8*)(xt + (((size_t)b * XT_H + hrow + 1) * XT_H + (w + 1)) * CINC + cg) = o;
    }

    // halo zeroing
    if (hrow == 0) {
        unsigned int* r0 = (unsigned int*)(xt + (size_t)b * XT_H * XT_H * CINC);
        for (int i = t; i < XT_H * CINC / 2; i += 256) r0[i] = 0u;
    }
    if (hrow == HWDIM - 1) {
        unsigned int* r129 = (unsigned int*)(xt + ((size_t)b * XT_H + 129) * XT_H * CINC);
        for (int i = t; i < XT_H * CINC / 2; i += 256) r129[i] = 0u;
    }
    if (t < 64) {
        const int wc = (t < 32) ? 0 : 129;
        unsigned int* p = (unsigned int*)(xt + (((size_t)b * XT_H + hrow + 1) * XT_H + wc) * CINC);
        p[t & 31] = 0u;
    }
}

// ---------------------------------------------------------------------------
// mlp1: reduce partials -> pooled; h = relu(pooled/16384 @ w1 + b1)  [32,64]
// grid 32 (one block per b), 256 threads
// ---------------------------------------------------------------------------
__global__ __launch_bounds__(256) void mlp1_kernel(
        const float* __restrict__ partial, const float* __restrict__ w1,
        const float* __restrict__ b1, float* __restrict__ hout) {
    __shared__ float red[256];
    __shared__ float pooled_s[CINC];
    const int b = blockIdx.x, t = threadIdx.x;
    const int c = t & 63, q = t >> 6;
    float s = 0.0f;
    for (int r = 0; r < 32; ++r)
        s += partial[((size_t)b * HWDIM + q * 32 + r) * CINC + c];
    red[t] = s;
    __syncthreads();
    if (t < 64)
        pooled_s[t] = (red[t] + red[t + 64] + red[t + 128] + red[t + 192]) * (1.0f / NPIX);
    __syncthreads();
    if (t < 64) {
        const int j = t;
        float acc = b1[j];
        for (int k = 0; k < CINC; ++k)
            acc = fmaf(pooled_s[k], w1[k * ADIMC + j], acc);
        hout[b * ADIMC + j] = fmaxf(acc, 0.0f);
    }
}

// ---------------------------------------------------------------------------
// adapt: a = tanh(h @ w2 + b2); adapted = base_w + scale*a
// emitted bf16 in layout [b][e=ky*3+kx][cout][cin]
// ---------------------------------------------------------------------------
__global__ __launch_bounds__(320) void adapt_kernel(
        const float* __restrict__ hin, const float* __restrict__ w2,
        const float* __restrict__ b2, const float* __restrict__ base_w,
        const float* __restrict__ scale_p, unsigned short* __restrict__ adp) {
    __shared__ float lh[NB * ADIMC];
    __shared__ unsigned short lo[288 * 33];
    const int t = threadIdx.x, blk = blockIdx.x;
    for (int i = t; i < NB * ADIMC; i += 320) lh[i] = hin[i];
    __syncthreads();
    const float sc = scale_p[0];

    if (t < 288) {
        const int j = blk * 288 + t;
        float acc[NB];
        #pragma unroll
        for (int b = 0; b < NB; ++b) acc[b] = 0.0f;
        for (int k = 0; k < ADIMC; ++k) {
            const float wv = w2[(size_t)k * WTOT + j];
            #pragma unroll
            for (int b = 0; b < NB; ++b) acc[b] = fmaf(lh[b * ADIMC + k], wv, acc[b]);
        }
        const float bw = base_w[j], bb = b2[j];
        #pragma unroll
        for (int b = 0; b < NB; ++b) {
            const float val = bw + sc * tanhf(acc[b] + bb);
            lo[t * 33 + b] = f2bf(val);
        }
    }
    __syncthreads();

    const int co = blk >> 1, ci0 = (blk & 1) * 32;
    for (int o = t; o < 9216; o += 320) {
        const int b = o / 288;
        const int rem = o - b * 288;
        const int e = rem >> 5, ci = rem & 31;
        adp[(((size_t)b * 9 + e) * COUTC + co) * CINC + ci0 + ci] = lo[(ci * 9 + e) * 33 + b];
    }
}

// ---------------------------------------------------------------------------
// conv: 9 shifted GEMMs via mfma_f32_16x16x32_bf16
// block: 256 thr (4 waves), M=64 (all couts), N=256 pixels (2 rows x 128)
// NEW: 3-slot register rotation, depth-2 prefetch of (A,B) fragment sets;
//      __launch_bounds__(256,2) gives the scheduler a 256-VGPR budget so the
//      24 in-flight fragment loads stay hoisted ahead of their MFMAs.
// grid (64 tiles, 32 b)
// ---------------------------------------------------------------------------
__global__ __launch_bounds__(256, 2) void conv_kernel(
        const unsigned short* __restrict__ xt, const unsigned short* __restrict__ adp,
        const float* __restrict__ base_b, float* __restrict__ out) {
    const int b = blockIdx.y, tile = blockIdx.x, t = threadIdx.x;
    const int wv = t >> 6, lane = t & 63, lm = lane & 15, lq = lane >> 4;
    const int h0 = tile * 2 + (wv >> 1);
    const int wc = (wv & 1) * 64;

    f32x4 acc[4][4];
    #pragma unroll
    for (int mi = 0; mi < 4; ++mi)
        #pragma unroll
        for (int ni = 0; ni < 4; ++ni) acc[mi][ni] = (f32x4){0.f, 0.f, 0.f, 0.f};

    // A: adp[b][e][cout][cin]; lane: cout = mi*16+lm, cin = kc*32 + lq*8
    const unsigned short* Ab = adp + (((size_t)b * 9) * COUTC + lm) * CINC + lq * 8;
    // B: xt[b][h0+ky][wc+lm+ni*16+kx][kc*32+lq*8]
    const unsigned short* Bb = xt + (((size_t)b * XT_H + h0) * XT_H + wc + lm) * CINC + lq * 8;

    short8 Af[3][4], Bf[3][4];

    auto load_step = [&](int s) {
        const int e = s >> 1, kc = s & 1;
        const int ky = e / 3, kx = e % 3;
        const int slot = s % 3;
        const unsigned short* Ae = Ab + (size_t)e * COUTC * CINC + kc * 32;
        const unsigned short* Bp = Bb + (size_t)(ky * XT_H + kx) * CINC + kc * 32;
        #pragma unroll
        for (int mi = 0; mi < 4; ++mi)
            Af[slot][mi] = *(const short8*)(Ae + mi * 16 * CINC);
        #pragma unroll
        for (int ni = 0; ni < 4; ++ni)
            Bf[slot][ni] = *(const short8*)(Bp + ni * 16 * CINC);
    };

    load_step(0);
    load_step(1);
    #pragma unroll
    for (int s = 0; s < 18; ++s) {
        if (s + 2 < 18) load_step(s + 2);
        const int slot = s % 3;
        #pragma unroll
        for (int mi = 0; mi < 4; ++mi)
            #pragma unroll
            for (int ni = 0; ni < 4; ++ni)
                acc[mi][ni] = __builtin_amdgcn_mfma_f32_16x16x32_bf16(
                    Af[slot][mi], Bf[slot][ni], acc[mi][ni], 0, 0, 0);
    }

    // epilogue: D row = lq*4+r (cout offset), col = lm (pixel offset)
    const int pixbase = h0 * HWDIM + wc + lm;
    #pragma unroll
    for (int mi = 0; mi < 4; ++mi) {
        #pragma unroll
        for (int r = 0; r < 4; ++r) {
            const int cout = mi * 16 + lq * 4 + r;
            const float bb = base_b[cout];
            #pragma unroll
            for (int ni = 0; ni < 4; ++ni)
                out[((size_t)(b * COUTC + cout) << 14) + pixbase + ni * 16] = acc[mi][ni][r] + bb;
        }
    }
}

// ---------------------------------------------------------------------------
extern "C" void kernel_launch(void* const* d_in, const int* in_sizes, int n_in,
                              void* d_out, int out_size, void* d_ws, size_t ws_size,
                              hipStream_t stream) {
    const float* x      = (const float*)d_in[0];
    const float* base_w = (const float*)d_in[1];
    const float* base_b = (const float*)d_in[2];
    const float* w1     = (const float*)d_in[3];
    const float* b1     = (const float*)d_in[4];
    const float* w2     = (const float*)d_in[5];
    const float* b2     = (const float*)d_in[6];
    const float* scale  = (const float*)d_in[7];
    float* out = (float*)d_out;

    // workspace layout
    unsigned short* xt  = (unsigned short*)d_ws;                        // 69,222,400 B
    unsigned short* adp = (unsigned short*)((char*)d_ws + 69222400);    //  2,359,296 B
    float* partial      = (float*)((char*)d_ws + 71581696);             //  1,048,576 B
    float* hbuf         = (float*)((char*)d_ws + 72630272);             //      8,192 B

    prep_kernel<<<dim3(HWDIM, NB), 256, 0, stream>>>(x, partial, xt);
    mlp1_kernel<<<NB, 256, 0, stream>>>(partial, w1, b1, hbuf);
    adapt_kernel<<<128, 320, 0, stream>>>(hbuf, w2, b2, base_w, scale, adp);
    conv_kernel<<<dim3(64, NB), 256, 0, stream>>>(xt, adp, base_b, out);
}